// Round 7
// baseline (706.720 us; speedup 1.0000x reference)
//
#include <hip/hip_runtime.h>
#include <stdint.h>

// HashGrid3D: L=16 levels, T=2^19 entries/level, F=2 features, trilinear.
//
// Structure (R7): temporal partitioning by level so the gathered working set
// is L2-resident per pass.
//   build_dense: levels 0..7 hash -> dense [z][y][x+pad] arrays in ws.
//   pass_dense2<6,7>: gather from dense arrays (2.1/4.3 MB, L2-resident);
//       x-pair = one 16B pair-load -> 4 requests/point; 2 points/thread.
//   pass_hash2<8..15>: one 4MB hash table per pass (fits XCD L2);
//       2 points/thread = 16 independent gathers in flight.
//   final_assemble<6>: levels 0..5 dense (2.1 MB resident, pair-loads)
//       + 10 SoA slices (streaming, nt) + 128B/point output (nt).
// ws: [0, 8.5MB) dense | [SOA_OFF, +10*8*n) SoA f2[level-6][n].
// Fallback tiers: R6 scheme (8 slices) -> R5 single kernel -> R1 all-hash.

constexpr int   LVL   = 16;
constexpr int   TBL   = 524288;          // 2^19
constexpr uint32_t TMASK = 0x7FFFFu;     // T-1
constexpr uint32_t P2 = 2654435761u;
constexpr uint32_t P3 = 805459861u;
// RES[l] = round(16 * (512/16)^(l/15))
constexpr int RESV[LVL] = {16, 20, 25, 32, 40, 51, 64, 81,
                           102, 128, 161, 203, 256, 323, 406, 512};

constexpr int NDL = 8;                   // levels 0..7 densified
// OFFE[l+1] = OFFE[l] + N^2*(N+1), N = RESV[l]  (entries are float2)
constexpr int OFFE[NDL + 1] = {0, 4352, 12752, 29002, 62794,
                               128394, 263646, 529886, 1067888};
constexpr size_t DENSE_BYTES = (size_t)1067888 * 8;   // 8,543,104 B
constexpr size_t SOA_OFF     = 8543232;               // 256B-aligned

typedef float f32x2 __attribute__((ext_vector_type(2)));
typedef float f32x4 __attribute__((ext_vector_type(4)));

// 16B pair-load from an 8B-aligned float2 pointer (x-adjacent corners).
__device__ __forceinline__ f32x4 load_pair(const float2* p) {
    f32x4 v;
    __builtin_memcpy(&v, p, 16);
    return v;
}

// ---------------- build kernel: hash table -> dense [z][y][x+pad] ----------
__global__ __launch_bounds__(256)
void build_dense(const float* __restrict__ tables, float2* __restrict__ dws)
{
    int tid = blockIdx.x * 256 + threadIdx.x;
    if (tid >= OFFE[NDL]) return;
    const float2* t2 = (const float2*)tables;
    #pragma unroll
    for (int l = 0; l < NDL; ++l) {
        if (tid < OFFE[l + 1]) {
            const int N = RESV[l], R = N + 1;      // compile-time per branch
            int idx = tid - OFFE[l];
            int xx = idx % R;
            int q  = idx / R;
            int yy = q % N;
            int zz = q / N;
            uint32_t xw = (xx == N) ? 0u : (uint32_t)xx;   // pad col = col 0
            uint32_t h = (xw ^ ((uint32_t)yy * P2) ^ ((uint32_t)zz * P3)) & TMASK;
            dws[tid] = t2[(size_t)l * TBL + h];
            return;
        }
    }
}

// ---------------- helpers ---------------------------------------------------
struct H8 { uint32_t h[8]; float tx, ty, tz; };

__device__ __forceinline__ H8 mk_h8(int N, float x, float y, float z)
{
    H8 r;
    float sx = x * (float)N, sy = y * (float)N, sz = z * (float)N;
    float fx = floorf(sx), fy = floorf(sy), fz = floorf(sz);
    r.tx = sx - fx; r.ty = sy - fy; r.tz = sz - fz;
    int ix = (int)fx, iy = (int)fy, iz = (int)fz;

    int ix0 = (ix >= N) ? ix - N : ix;        // ref wraps corner 0 too
    int iy0 = (iy >= N) ? iy - N : iy;
    int iz0 = (iz >= N) ? iz - N : iz;
    int ix1 = ix + 1; ix1 = (ix1 >= N) ? ix1 - N : ix1;
    int iy1 = iy + 1; iy1 = (iy1 >= N) ? iy1 - N : iy1;
    int iz1 = iz + 1; iz1 = (iz1 >= N) ? iz1 - N : iz1;

    uint32_t hx0 = (uint32_t)ix0;
    uint32_t hx1 = (uint32_t)ix1;
    uint32_t hy0 = (uint32_t)iy0 * P2;
    uint32_t hy1 = (uint32_t)iy1 * P2;
    uint32_t hz0 = (uint32_t)iz0 * P3;
    uint32_t hz1 = (uint32_t)iz1 * P3;

    r.h[0] = (hx0 ^ hy0 ^ hz0) & TMASK;
    r.h[1] = (hx1 ^ hy0 ^ hz0) & TMASK;
    r.h[2] = (hx0 ^ hy1 ^ hz0) & TMASK;
    r.h[3] = (hx1 ^ hy1 ^ hz0) & TMASK;
    r.h[4] = (hx0 ^ hy0 ^ hz1) & TMASK;
    r.h[5] = (hx1 ^ hy0 ^ hz1) & TMASK;
    r.h[6] = (hx0 ^ hy1 ^ hz1) & TMASK;
    r.h[7] = (hx1 ^ hy1 ^ hz1) & TMASK;
    return r;
}

struct D4 { int b00, b10, b01, b11; float tx, ty, tz; };

__device__ __forceinline__ D4 mk_d4(int N, float x, float y, float z)
{
    D4 r;
    const int R = N + 1;
    float sx = x * (float)N, sy = y * (float)N, sz = z * (float)N;
    float fx = floorf(sx), fy = floorf(sy), fz = floorf(sz);
    r.tx = sx - fx; r.ty = sy - fy; r.tz = sz - fz;
    int ix = (int)fx, iy = (int)fy, iz = (int)fz;

    int ix0 = (ix >= N) ? ix - N : ix;
    int iy0 = (iy >= N) ? iy - N : iy;
    int iz0 = (iz >= N) ? iz - N : iz;
    int iy1 = iy0 + 1; iy1 = (iy1 >= N) ? 0 : iy1;
    int iz1 = iz0 + 1; iz1 = (iz1 >= N) ? 0 : iz1;

    r.b00 = (iz0 * N + iy0) * R + ix0;
    r.b10 = (iz0 * N + iy1) * R + ix0;
    r.b01 = (iz1 * N + iy0) * R + ix0;
    r.b11 = (iz1 * N + iy1) * R + ix0;
    return r;
}

__device__ __forceinline__ void trilerp(float tx, float ty, float tz,
                                        float2 g000, float2 g100, float2 g010, float2 g110,
                                        float2 g001, float2 g101, float2 g011, float2 g111,
                                        float* __restrict__ o)
{
    float wx1 = tx, wx0 = 1.0f - tx;
    float wy1 = ty, wy0 = 1.0f - ty;
    float wz1 = tz, wz0 = 1.0f - tz;
    float wz0y0 = wy0 * wz0, wz0y1 = wy1 * wz0;
    float wz1y0 = wy0 * wz1, wz1y1 = wy1 * wz1;
    float w000 = wx0 * wz0y0, w100 = wx1 * wz0y0;
    float w010 = wx0 * wz0y1, w110 = wx1 * wz0y1;
    float w001 = wx0 * wz1y0, w101 = wx1 * wz1y0;
    float w011 = wx0 * wz1y1, w111 = wx1 * wz1y1;
    o[0] = w000*g000.x + w100*g100.x + w010*g010.x + w110*g110.x
         + w001*g001.x + w101*g101.x + w011*g011.x + w111*g111.x;
    o[1] = w000*g000.y + w100*g100.y + w010*g010.y + w110*g110.y
         + w001*g001.y + w101*g101.y + w011*g011.y + w111*g111.y;
}

// pair-load variant: q00=[g000|g100], q10=[g010|g110], q01=[g001|g101], q11=[g011|g111]
__device__ __forceinline__ void trilerp4(float tx, float ty, float tz,
                                         f32x4 q00, f32x4 q10, f32x4 q01, f32x4 q11,
                                         float* __restrict__ o)
{
    float wx1 = tx, wx0 = 1.0f - tx;
    float wy1 = ty, wy0 = 1.0f - ty;
    float wz1 = tz, wz0 = 1.0f - tz;
    float wz0y0 = wy0 * wz0, wz0y1 = wy1 * wz0;
    float wz1y0 = wy0 * wz1, wz1y1 = wy1 * wz1;
    float w000 = wx0 * wz0y0, w100 = wx1 * wz0y0;
    float w010 = wx0 * wz0y1, w110 = wx1 * wz0y1;
    float w001 = wx0 * wz1y0, w101 = wx1 * wz1y0;
    float w011 = wx0 * wz1y1, w111 = wx1 * wz1y1;
    o[0] = w000*q00.x + w100*q00.z + w010*q10.x + w110*q10.z
         + w001*q01.x + w101*q01.z + w011*q11.x + w111*q11.z;
    o[1] = w000*q00.y + w100*q00.w + w010*q10.y + w110*q10.w
         + w001*q01.y + w101*q01.w + w011*q11.y + w111*q11.w;
}

// ---------------- per-level hash pass: 2 points/thread ---------------------
template<int LH>
__global__ __launch_bounds__(256)
void pass_hash2(const float* __restrict__ xyt,
                const float* __restrict__ tables,
                float* __restrict__ soa, int n)   // soa = this level's slice
{
    int t = blockIdx.x * 256 + threadIdx.x;
    int p0 = 2 * t;
    if (p0 >= n) return;
    bool two = (p0 + 1 < n);

    const float* xb = xyt + 6 * (size_t)t;
    f32x2 a = __builtin_nontemporal_load((const f32x2*)xb);       // x0 y0
    float x0 = a.x, y0 = a.y, z0, x1, y1, z1;
    if (two) {
        f32x2 m = __builtin_nontemporal_load((const f32x2*)(xb + 2));  // z0 x1
        f32x2 c = __builtin_nontemporal_load((const f32x2*)(xb + 4));  // y1 z1
        z0 = m.x; x1 = m.y; y1 = c.x; z1 = c.y;
    } else {
        z0 = __builtin_nontemporal_load(xb + 2);
        x1 = x0; y1 = y0; z1 = z0;
    }

    const int N = RESV[LH];
    const float2* __restrict__ tbl = (const float2*)tables + (size_t)LH * TBL;

    H8 A = mk_h8(N, x0, y0, z0);
    H8 B = mk_h8(N, x1, y1, z1);

    float2 gA[8], gB[8];
    #pragma unroll
    for (int i = 0; i < 8; ++i) gA[i] = tbl[A.h[i]];
    #pragma unroll
    for (int i = 0; i < 8; ++i) gB[i] = tbl[B.h[i]];

    float r0[2], r1[2];
    trilerp(A.tx, A.ty, A.tz, gA[0], gA[1], gA[2], gA[3],
            gA[4], gA[5], gA[6], gA[7], r0);
    trilerp(B.tx, B.ty, B.tz, gB[0], gB[1], gB[2], gB[3],
            gB[4], gB[5], gB[6], gB[7], r1);

    if (two) {
        f32x4 v = { r0[0], r0[1], r1[0], r1[1] };
        __builtin_nontemporal_store(v, (f32x4*)(soa + 4 * (size_t)t));
    } else {
        f32x2 v = { r0[0], r0[1] };
        __builtin_nontemporal_store(v, (f32x2*)(soa + 4 * (size_t)t));
    }
}

// ---------------- per-level dense pass (levels 6/7): 2 points/thread -------
template<int LD>
__global__ __launch_bounds__(256)
void pass_dense2(const float* __restrict__ xyt,
                 const float2* __restrict__ dense,
                 float* __restrict__ soa, int n)
{
    int t = blockIdx.x * 256 + threadIdx.x;
    int p0 = 2 * t;
    if (p0 >= n) return;
    bool two = (p0 + 1 < n);

    const float* xb = xyt + 6 * (size_t)t;
    f32x2 a = __builtin_nontemporal_load((const f32x2*)xb);
    float x0 = a.x, y0 = a.y, z0, x1, y1, z1;
    if (two) {
        f32x2 m = __builtin_nontemporal_load((const f32x2*)(xb + 2));
        f32x2 c = __builtin_nontemporal_load((const f32x2*)(xb + 4));
        z0 = m.x; x1 = m.y; y1 = c.x; z1 = c.y;
    } else {
        z0 = __builtin_nontemporal_load(xb + 2);
        x1 = x0; y1 = y0; z1 = z0;
    }

    const int N = RESV[LD];
    const float2* __restrict__ dl = dense + OFFE[LD];

    D4 A = mk_d4(N, x0, y0, z0);
    D4 B = mk_d4(N, x1, y1, z1);

    f32x4 qA0 = load_pair(dl + A.b00), qA1 = load_pair(dl + A.b10);
    f32x4 qA2 = load_pair(dl + A.b01), qA3 = load_pair(dl + A.b11);
    f32x4 qB0 = load_pair(dl + B.b00), qB1 = load_pair(dl + B.b10);
    f32x4 qB2 = load_pair(dl + B.b01), qB3 = load_pair(dl + B.b11);

    float r0[2], r1[2];
    trilerp4(A.tx, A.ty, A.tz, qA0, qA1, qA2, qA3, r0);
    trilerp4(B.tx, B.ty, B.tz, qB0, qB1, qB2, qB3, r1);

    if (two) {
        f32x4 v = { r0[0], r0[1], r1[0], r1[1] };
        __builtin_nontemporal_store(v, (f32x4*)(soa + 4 * (size_t)t));
    } else {
        f32x2 v = { r0[0], r0[1] };
        __builtin_nontemporal_store(v, (f32x2*)(soa + 4 * (size_t)t));
    }
}

// ---------------- final: dense levels 0..NDF-1 + (16-NDF) SoA slices -------
template<int NDF>
__global__ __launch_bounds__(256)
void final_assemble(const float* __restrict__ xyt,
                    const float2* __restrict__ dense,
                    const float* __restrict__ soa,   // f2[16-NDF][n]
                    float* __restrict__ out, int n)
{
    int p = blockIdx.x * 256 + threadIdx.x;
    if (p >= n) return;

    float x = xyt[3 * p + 0];
    float y = xyt[3 * p + 1];
    float z = xyt[3 * p + 2];

    float outv[2 * LVL];

    #pragma unroll
    for (int l = 0; l < NDF; ++l) {
        const int N = RESV[l];
        const float2* __restrict__ dl = dense + OFFE[l];
        D4 d = mk_d4(N, x, y, z);
        f32x4 q0 = load_pair(dl + d.b00), q1 = load_pair(dl + d.b10);
        f32x4 q2 = load_pair(dl + d.b01), q3 = load_pair(dl + d.b11);
        trilerp4(d.tx, d.ty, d.tz, q0, q1, q2, q3, &outv[2 * l]);
    }

    #pragma unroll
    for (int s = 0; s < 16 - NDF; ++s) {
        f32x2 v = __builtin_nontemporal_load(
            (const f32x2*)(soa + 2 * ((size_t)s * (size_t)n + (size_t)p)));
        outv[2 * (NDF + s) + 0] = v.x;
        outv[2 * (NDF + s) + 1] = v.y;
    }

    float* o = out + (size_t)p * 32;
    #pragma unroll
    for (int i = 0; i < 8; ++i) {
        f32x4 v = { outv[4*i+0], outv[4*i+1], outv[4*i+2], outv[4*i+3] };
        __builtin_nontemporal_store(v, (f32x4*)(o + 4 * i));
    }
}

// ---------------- fallback B: R5 dense+hash single kernel ------------------
__global__ __launch_bounds__(256)
void hashgrid3d_dense(const float* __restrict__ xyt,
                      const float* __restrict__ tables,
                      const float2* __restrict__ dense,
                      float* __restrict__ out, int n)
{
    int p = blockIdx.x * 256 + threadIdx.x;
    if (p >= n) return;

    float x = xyt[3 * p + 0];
    float y = xyt[3 * p + 1];
    float z = xyt[3 * p + 2];

    float outv[2 * LVL];

    #pragma unroll
    for (int l = 0; l < NDL; ++l) {
        const int N = RESV[l];
        const float2* __restrict__ dl = dense + OFFE[l];
        D4 d = mk_d4(N, x, y, z);
        f32x4 q0 = load_pair(dl + d.b00), q1 = load_pair(dl + d.b10);
        f32x4 q2 = load_pair(dl + d.b01), q3 = load_pair(dl + d.b11);
        trilerp4(d.tx, d.ty, d.tz, q0, q1, q2, q3, &outv[2 * l]);
    }

    #pragma unroll
    for (int l = NDL; l < LVL; ++l) {
        const int N = RESV[l];
        const float2* __restrict__ tbl = (const float2*)tables + (size_t)l * TBL;
        H8 hh = mk_h8(N, x, y, z);
        float2 g[8];
        #pragma unroll
        for (int i = 0; i < 8; ++i) g[i] = tbl[hh.h[i]];
        trilerp(hh.tx, hh.ty, hh.tz, g[0], g[1], g[2], g[3],
                g[4], g[5], g[6], g[7], &outv[2 * l]);
    }

    float4* o = (float4*)(out + (size_t)p * 32);
    #pragma unroll
    for (int i = 0; i < 8; ++i)
        o[i] = ((const float4*)outv)[i];
}

// ---------------- fallback C: R1 all-hash kernel ---------------------------
__global__ __launch_bounds__(256)
void hashgrid3d_hash(const float* __restrict__ xyt,
                     const float* __restrict__ tables,
                     float* __restrict__ out, int n)
{
    int p = blockIdx.x * 256 + threadIdx.x;
    if (p >= n) return;

    float x = xyt[3 * p + 0];
    float y = xyt[3 * p + 1];
    float z = xyt[3 * p + 2];

    float outv[2 * LVL];

    #pragma unroll
    for (int l = 0; l < LVL; ++l) {
        const int N = RESV[l];
        const float2* __restrict__ tbl = (const float2*)tables + (size_t)l * TBL;
        H8 hh = mk_h8(N, x, y, z);
        float2 g[8];
        #pragma unroll
        for (int i = 0; i < 8; ++i) g[i] = tbl[hh.h[i]];
        trilerp(hh.tx, hh.ty, hh.tz, g[0], g[1], g[2], g[3],
                g[4], g[5], g[6], g[7], &outv[2 * l]);
    }

    float4* o = (float4*)(out + (size_t)p * 32);
    #pragma unroll
    for (int i = 0; i < 8; ++i)
        o[i] = ((const float4*)outv)[i];
}

extern "C" void kernel_launch(void* const* d_in, const int* in_sizes, int n_in,
                              void* d_out, int out_size, void* d_ws, size_t ws_size,
                              hipStream_t stream) {
    const float* xyt    = (const float*)d_in[0];   // (1048576, 3) f32
    const float* tables = (const float*)d_in[1];   // (16, 524288, 2) f32
    float* out = (float*)d_out;                    // (1048576, 32) f32
    int n = in_sizes[0] / 3;
    int blocks  = (n + 255) / 256;
    int blocks2 = ((n + 1) / 2 + 255) / 256;

    size_t need_full = SOA_OFF + (size_t)80 * (size_t)n;   // 10 slices
    size_t need_mid  = SOA_OFF + (size_t)64 * (size_t)n;   // 8 slices (R6)

    if (d_ws != nullptr && ws_size >= need_full) {
        int bblocks = (OFFE[NDL] + 255) / 256;
        build_dense<<<bblocks, 256, 0, stream>>>(tables, (float2*)d_ws);

        float* soa = (float*)((char*)d_ws + SOA_OFF);
        size_t stride = 2 * (size_t)n;
        const float2* dense = (const float2*)d_ws;
        // slice s = level 6+s
        pass_dense2< 6><<<blocks2, 256, 0, stream>>>(xyt, dense, soa + 0 * stride, n);
        pass_dense2< 7><<<blocks2, 256, 0, stream>>>(xyt, dense, soa + 1 * stride, n);
        pass_hash2 < 8><<<blocks2, 256, 0, stream>>>(xyt, tables, soa + 2 * stride, n);
        pass_hash2 < 9><<<blocks2, 256, 0, stream>>>(xyt, tables, soa + 3 * stride, n);
        pass_hash2 <10><<<blocks2, 256, 0, stream>>>(xyt, tables, soa + 4 * stride, n);
        pass_hash2 <11><<<blocks2, 256, 0, stream>>>(xyt, tables, soa + 5 * stride, n);
        pass_hash2 <12><<<blocks2, 256, 0, stream>>>(xyt, tables, soa + 6 * stride, n);
        pass_hash2 <13><<<blocks2, 256, 0, stream>>>(xyt, tables, soa + 7 * stride, n);
        pass_hash2 <14><<<blocks2, 256, 0, stream>>>(xyt, tables, soa + 8 * stride, n);
        pass_hash2 <15><<<blocks2, 256, 0, stream>>>(xyt, tables, soa + 9 * stride, n);

        final_assemble<6><<<blocks, 256, 0, stream>>>(xyt, dense, soa, out, n);
    } else if (d_ws != nullptr && ws_size >= need_mid) {
        // R6 scheme: 8 hash slices, dense 0..7 in final
        int bblocks = (OFFE[NDL] + 255) / 256;
        build_dense<<<bblocks, 256, 0, stream>>>(tables, (float2*)d_ws);

        float* soa = (float*)((char*)d_ws + SOA_OFF);
        size_t stride = 2 * (size_t)n;
        const float2* dense = (const float2*)d_ws;
        pass_hash2 < 8><<<blocks2, 256, 0, stream>>>(xyt, tables, soa + 0 * stride, n);
        pass_hash2 < 9><<<blocks2, 256, 0, stream>>>(xyt, tables, soa + 1 * stride, n);
        pass_hash2 <10><<<blocks2, 256, 0, stream>>>(xyt, tables, soa + 2 * stride, n);
        pass_hash2 <11><<<blocks2, 256, 0, stream>>>(xyt, tables, soa + 3 * stride, n);
        pass_hash2 <12><<<blocks2, 256, 0, stream>>>(xyt, tables, soa + 4 * stride, n);
        pass_hash2 <13><<<blocks2, 256, 0, stream>>>(xyt, tables, soa + 5 * stride, n);
        pass_hash2 <14><<<blocks2, 256, 0, stream>>>(xyt, tables, soa + 6 * stride, n);
        pass_hash2 <15><<<blocks2, 256, 0, stream>>>(xyt, tables, soa + 7 * stride, n);

        final_assemble<8><<<blocks, 256, 0, stream>>>(xyt, dense, soa, out, n);
    } else if (d_ws != nullptr && ws_size >= DENSE_BYTES) {
        int bblocks = (OFFE[NDL] + 255) / 256;
        build_dense<<<bblocks, 256, 0, stream>>>(tables, (float2*)d_ws);
        hashgrid3d_dense<<<blocks, 256, 0, stream>>>(xyt, tables,
                                                     (const float2*)d_ws, out, n);
    } else {
        hashgrid3d_hash<<<blocks, 256, 0, stream>>>(xyt, tables, out, n);
    }
}